// Round 11
// baseline (68.153 us; speedup 1.0000x reference)
//
#include <hip/hip_runtime.h>
#include <hip/hip_bf16.h>

// EdgeLearnGNN: B=16, N=64, F=1024, K=13, C=2
// Round 10: eliminate the gpart round-trip. The GEMM g=x@W^T no longer runs as a
// separate producer in K1 (8MB write + 16MB cross-XCD read + full serialization
// before K2); instead each K2 block computes its OWN 64x64 g-tile
// (x[b] @ W[f0:f0+64,:]^T, K=1024, bf16 MFMA) staged straight from f32 in L2.
// K1 is spart-only. K2 = 512 threads (8 waves = 4 M-split x 2 N-split,
// 2 waves/SIMD). Boundary cost is calibrated at ~2-3us (r10: ticket merge saved
// 2.2), so the ~60us in bodies is the target now.
//   K1: 256 blocks: spart tiles (b,ft)
//   K2: 256 blocks x 512: g-tile GEMM + adj recompute + h2=(A+I)g+gin_b + BN1 part
//   K3: 64 blocks: BN1 reduce + folded mix + conv13 + BN2 partials + [mod-ticket: head]

typedef __attribute__((ext_vector_type(8))) __bf16 bf16x8;
typedef __attribute__((ext_vector_type(4))) float f32x4;

__device__ __forceinline__ unsigned short f2bf(float f) {
  union { float f; unsigned int u; } v; v.f = f;
  unsigned int r = v.u + 0x7FFFu + ((v.u >> 16) & 1u);   // RNE, finite values only
  return (unsigned short)(r >> 16);
}

// ---------------- K1: spart tile (b,ft): partial weighted-L1 scores ----------------
__global__ __launch_bounds__(256) void k1_spart(
    const float* __restrict__ x, const float* __restrict__ w,
    float* __restrict__ spart) {
  __shared__ __align__(16) float xt[64 * 68];
  __shared__ __align__(16) float wt[64];
  int t = threadIdx.x, bid = blockIdx.x;
  int b = bid >> 4, ft = bid & 15, f0 = ft * 64;
  for (int c = 0; c < 16; ++c) {
    int idx = c * 256 + t;
    int n = idx >> 6, f = idx & 63;
    xt[n * 68 + f] = x[b * 65536 + n * 1024 + f0 + f];
  }
  if (t < 64) wt[t] = w[f0 + t];
  __syncthreads();
  int i0 = (t >> 4) * 4, j0 = (t & 15) * 4;
  float acc[4][4];
#pragma unroll
  for (int ii = 0; ii < 4; ++ii)
#pragma unroll
    for (int jj = 0; jj < 4; ++jj) acc[ii][jj] = 0.f;
  for (int f = 0; f < 64; f += 4) {
    float4 wv = *reinterpret_cast<const float4*>(&wt[f]);
    float4 av[4], bv[4];
#pragma unroll
    for (int ii = 0; ii < 4; ++ii) av[ii] = *reinterpret_cast<const float4*>(&xt[(i0 + ii) * 68 + f]);
#pragma unroll
    for (int jj = 0; jj < 4; ++jj) bv[jj] = *reinterpret_cast<const float4*>(&xt[(j0 + jj) * 68 + f]);
#pragma unroll
    for (int ii = 0; ii < 4; ++ii)
#pragma unroll
      for (int jj = 0; jj < 4; ++jj) {
        acc[ii][jj] += fabsf(av[ii].x - bv[jj].x) * wv.x
                     + fabsf(av[ii].y - bv[jj].y) * wv.y
                     + fabsf(av[ii].z - bv[jj].z) * wv.z
                     + fabsf(av[ii].w - bv[jj].w) * wv.w;
      }
  }
  float* out = spart + (size_t)bid * 4096;
#pragma unroll
  for (int ii = 0; ii < 4; ++ii)
#pragma unroll
    for (int jj = 0; jj < 4; ++jj)
      out[(i0 + ii) * 64 + (j0 + jj)] = acc[ii][jj];
}

// ---- K2: per-block g-tile GEMM + adj recompute + h2 + BN1 partials (512 thr) ----
// XCD-swizzled: 16 blocks of batch b share one XCD -> x[b], spart[b] L2-resident.
__global__ __launch_bounds__(512) void k2_gemm_adj_h2(
    const float* __restrict__ x, const float* __restrict__ gin_W,
    const float* __restrict__ spart, const float* __restrict__ gin_b,
    float* __restrict__ dout, float* __restrict__ h2, float* __restrict__ part) {
  __shared__ __align__(16) float gt[64 * 68];
  __shared__ __align__(16) union {
    struct { unsigned short A4[4][64 * 72]; unsigned short B4[4][64 * 72]; } st;   // 73.7 KB
    struct { float adjs[64 * 65]; float csum[512]; float cinv[64]; } aj;           // 18.9 KB
  } sm;
  int t = threadIdx.x, bid = blockIdx.x;
  int xcd = bid & 7, local = bid >> 3;
  int b = (xcd << 1) | (local & 1);
  int ft = local >> 1;
  int f0 = ft * 64;
  int wave = t >> 6, lane = t & 63;
  int wr = (wave & 3) * 16, wc = (wave >> 2) * 32;   // 4 M-split x 2 N-split
  int lrow = lane & 15, kg = lane >> 4;

  // ---- GEMM: g[i][f] = sum_k x[b][i][k] * W[f0+f][k], K=1024 in 4 chunks of 256 ----
  f32x4 acc[2] = {{0.f,0.f,0.f,0.f},{0.f,0.f,0.f,0.f}};
  for (int bc = 0; bc < 4; ++bc) {
    int kc = bc * 256;
#pragma unroll
    for (int u = 0; u < 8; ++u) {                 // stage A: x rows 64 x 256k (f32->bf16)
      int idx4 = u * 512 + t;
      int sub = idx4 >> 10, rem = idx4 & 1023;
      int row = rem >> 4, kq = rem & 15;
      float4 va = *reinterpret_cast<const float4*>(&x[(size_t)b * 65536 + row * 1024 + kc + sub * 64 + kq * 4]);
      ushort4 ua; ua.x = f2bf(va.x); ua.y = f2bf(va.y); ua.z = f2bf(va.z); ua.w = f2bf(va.w);
      *reinterpret_cast<ushort4*>(&sm.st.A4[sub][row * 72 + kq * 4]) = ua;
      float4 vb = *reinterpret_cast<const float4*>(&gin_W[(size_t)(f0 + row) * 1024 + kc + sub * 64 + kq * 4]);
      ushort4 ub; ub.x = f2bf(vb.x); ub.y = f2bf(vb.y); ub.z = f2bf(vb.z); ub.w = f2bf(vb.w);
      *reinterpret_cast<ushort4*>(&sm.st.B4[sub][row * 72 + kq * 4]) = ub;
    }
    __syncthreads();
#pragma unroll
    for (int sub = 0; sub < 4; ++sub)
#pragma unroll
      for (int ks = 0; ks < 2; ++ks) {
        bf16x8 a = *reinterpret_cast<const bf16x8*>(&sm.st.A4[sub][(wr + lrow) * 72 + ks * 32 + kg * 8]);
#pragma unroll
        for (int c = 0; c < 2; ++c) {
          bf16x8 bb = *reinterpret_cast<const bf16x8*>(&sm.st.B4[sub][(wc + c * 16 + lrow) * 72 + ks * 32 + kg * 8]);
          acc[c] = __builtin_amdgcn_mfma_f32_16x16x32_bf16(a, bb, acc[c], 0, 0, 0);
        }
      }
    __syncthreads();
  }
  // acc -> gt  (C/D: row = (lane>>4)*4 + reg, col = lane&15)
#pragma unroll
  for (int c = 0; c < 2; ++c)
#pragma unroll
    for (int r = 0; r < 4; ++r)
      gt[(wr + kg * 4 + r) * 68 + wc + c * 16 + lrow] = acc[c][r];
  __syncthreads();   // gt ready; staging LDS dead -> adj arrays live

  // ---- adj[b] recompute (redundant per ft; ft==0 writes dout) ----
  int jl = t & 63, q = wave;                     // q 0..7: rows q*8..q*8+7
  float v[8];
#pragma unroll
  for (int r = 0; r < 8; ++r) v[r] = 0.f;
  for (int ft2 = 0; ft2 < 16; ++ft2) {
    const float* p = spart + (size_t)(b * 16 + ft2) * 4096 + jl;
#pragma unroll
    for (int r = 0; r < 8; ++r) v[r] += p[(q * 8 + r) * 64];
  }
  float partsum = 0.f;
#pragma unroll
  for (int r = 0; r < 8; ++r) {
    float e = expf(-fmaxf(v[r], 0.f));
    sm.aj.adjs[(q * 8 + r) * 65 + jl] = e;
    partsum += e;
  }
  sm.aj.csum[q * 64 + jl] = partsum;
  __syncthreads();
  if (t < 64) {
    float s = 0.f;
#pragma unroll
    for (int g2 = 0; g2 < 8; ++g2) s += sm.aj.csum[g2 * 64 + t];
    sm.aj.cinv[t] = 1.f / s;
  }
  __syncthreads();
  float ci = sm.aj.cinv[jl];
  float* doutAdj = dout + 32 + (size_t)b * 4096;
#pragma unroll
  for (int r = 0; r < 8; ++r) {
    float a = sm.aj.adjs[(q * 8 + r) * 65 + jl] * ci;
    sm.aj.adjs[(q * 8 + r) * 65 + jl] = a;
    if (ft == 0) doutAdj[(q * 8 + r) * 64 + jl] = a;
  }
  __syncthreads();

  // ---- h2 tile = gt + adj@gt + gin_b; BN1 partials. 2 rows x 4 cols per thread ----
  int i0 = (t >> 4) * 2, fl = (t & 15) * 4;
  float4 gbv = *reinterpret_cast<const float4*>(&gin_b[f0 + fl]);
  float4 acc4[2];
  acc4[0] = *reinterpret_cast<const float4*>(&gt[i0 * 68 + fl]);         // identity
  acc4[1] = *reinterpret_cast<const float4*>(&gt[(i0 + 1) * 68 + fl]);
  for (int j = 0; j < 64; ++j) {
    float4 gv = *reinterpret_cast<const float4*>(&gt[j * 68 + fl]);
    float a0 = sm.aj.adjs[i0 * 65 + j], a1 = sm.aj.adjs[(i0 + 1) * 65 + j];
    acc4[0].x += a0 * gv.x; acc4[0].y += a0 * gv.y; acc4[0].z += a0 * gv.z; acc4[0].w += a0 * gv.w;
    acc4[1].x += a1 * gv.x; acc4[1].y += a1 * gv.y; acc4[1].z += a1 * gv.z; acc4[1].w += a1 * gv.w;
  }
  float rs[2], rq[2];
#pragma unroll
  for (int ii = 0; ii < 2; ++ii) {
    acc4[ii].x += gbv.x; acc4[ii].y += gbv.y; acc4[ii].z += gbv.z; acc4[ii].w += gbv.w;
    *reinterpret_cast<float4*>(&h2[(size_t)(b * 64 + i0 + ii) * 1024 + f0 + fl]) = acc4[ii];
    rs[ii] = (acc4[ii].x + acc4[ii].y) + (acc4[ii].z + acc4[ii].w);
    rq[ii] = (acc4[ii].x * acc4[ii].x + acc4[ii].y * acc4[ii].y)
           + (acc4[ii].z * acc4[ii].z + acc4[ii].w * acc4[ii].w);
  }
#pragma unroll
  for (int m = 1; m < 16; m <<= 1) {
#pragma unroll
    for (int r = 0; r < 2; ++r) {
      rs[r] += __shfl_xor(rs[r], m, 64);
      rq[r] += __shfl_xor(rq[r], m, 64);
    }
  }
  if ((t & 15) == 0) {
    float* pp = part + (size_t)(b * 16 + ft) * 128;
#pragma unroll
    for (int r = 0; r < 2; ++r) {
      int n = i0 + r;
      pp[2 * n]     = rs[r];
      pp[2 * n + 1] = rq[r];
    }
  }
}

// ---- K3: 64 blocks (b, 256-f quarter). BN1 reduce + folded mix + conv13 +
//      BN2 partials; modulo terminal ticket -> last arriver runs the head inline. ----
__global__ __launch_bounds__(256) void k3_y_head(
    const float* __restrict__ h2, const float* __restrict__ part,
    const float* __restrict__ lc_W, const float* __restrict__ lc_b,
    const float* __restrict__ bn1_g, const float* __restrict__ bn1_b,
    const float* __restrict__ conv_W, const float* __restrict__ conv_b,
    const float* __restrict__ bn2_g, const float* __restrict__ bn2_b,
    const float* __restrict__ out_W, const float* __restrict__ out_b,
    float* __restrict__ y2, float* __restrict__ bn2part,
    float* __restrict__ dout, unsigned* __restrict__ bar) {
  __shared__ float redp[2][128];
  __shared__ float cls[64], dds[64];
  __shared__ float yloc[268];
  __shared__ float red[256], red2[256];
  __shared__ float c0s;
  __shared__ unsigned tk;
  int t = threadIdx.x, bid = blockIdx.x;
  int b = ((bid & 7) << 1) | ((bid >> 3) & 1);
  int fq = bid >> 4;
  int f0 = fq * 256;
  {
    int k = t & 127, h = t >> 7;
    float s = 0.f;
    const float* pp = part + (size_t)h * 128 * 128 + k;
    for (int p = 0; p < 128; ++p) s += pp[(size_t)p * 128];
    redp[h][k] = s;
  }
  __syncthreads();
  if (t < 64) {
    float sum = redp[0][2 * t] + redp[1][2 * t];
    float sq  = redp[0][2 * t + 1] + redp[1][2 * t + 1];
    float m = sum * (1.f / 16384.f);
    float var = sq * (1.f / 16384.f) - m * m;     // biased, as jnp.var
    float inv = 1.f / sqrtf(var + 1e-5f);
    float g = bn1_g[t], be = bn1_b[t], lw = lc_W[t];
    cls[t] = lw * g * inv;
    dds[t] = lw * (be - m * inv * g);
  }
  __syncthreads();
  if (t == 0) {
    float s = 0.f;
    for (int n = 0; n < 64; ++n) s += dds[n];
    c0s = s + lc_b[0];
  }
  __syncthreads();
  float c0 = c0s;
  for (int idx = t; idx < 268; idx += 256) {
    int f = f0 - 6 + idx;
    float acc = 0.f;
    if (f >= 0 && f < 1024) {
      acc = c0;
      const float* col = h2 + (size_t)(b * 64) * 1024 + f;
      for (int n = 0; n < 64; ++n) acc += cls[n] * col[(size_t)n * 1024];
    }
    yloc[idx] = acc;
  }
  __syncthreads();
  float cw[13];
#pragma unroll
  for (int k = 0; k < 13; ++k) cw[k] = conv_W[k];
  float vv = conv_b[0];
#pragma unroll
  for (int k = 0; k < 13; ++k) vv += yloc[t + k] * cw[k];
  y2[b * 1024 + f0 + t] = vv;
  red[t] = vv; red2[t] = vv * vv;
  __syncthreads();
  for (int off = 128; off > 0; off >>= 1) {
    if (t < off) { red[t] += red[t + off]; red2[t] += red2[t + off]; }
    __syncthreads();
  }
  if (t == 0) {
    int dchunk = b * 4 + fq;
    bn2part[2 * dchunk] = red[0]; bn2part[2 * dchunk + 1] = red2[0];
  }

  // --- modulo terminal ticket: exactly one block per launch draws (tk&63)==63,
  //     zero waiting (all other 63 blocks already release-fenced). Never reset. ---
  __syncthreads();                                 // all block stores drained (vmcnt)
  if (t == 0) { __threadfence(); tk = atomicAdd(bar, 1u); }
  __syncthreads();
  if ((tk & 63u) != 63u) return;
  __threadfence();                                 // acquire: see all blocks' y2/bn2part

  {
    float S = 0.f, S2 = 0.f;
    for (int i = 0; i < 64; ++i) { S += bn2part[2 * i]; S2 += bn2part[2 * i + 1]; }
    float m2 = S * (1.f / 16384.f);
    float inv2 = 1.f / sqrtf(S2 * (1.f / 16384.f) - m2 * m2 + 1e-5f);
    float g2 = bn2_g[0] * inv2, be2 = bn2_b[0];
    int hb = t >> 4, seg = t & 15;
    const float4* yv = reinterpret_cast<const float4*>(&y2[hb * 1024 + seg * 64]);
    const float4* w0 = reinterpret_cast<const float4*>(&out_W[seg * 64]);
    const float4* w1 = reinterpret_cast<const float4*>(&out_W[1024 + seg * 64]);
    float a0 = 0.f, a1 = 0.f;
#pragma unroll 4
    for (int u = 0; u < 16; ++u) {
      float4 y4 = yv[u], cc0 = w0[u], cc1 = w1[u];
      float vx = fmaxf((y4.x - m2) * g2 + be2, 0.f);
      float vy = fmaxf((y4.y - m2) * g2 + be2, 0.f);
      float vz = fmaxf((y4.z - m2) * g2 + be2, 0.f);
      float vw = fmaxf((y4.w - m2) * g2 + be2, 0.f);
      a0 += vx * cc0.x + vy * cc0.y + vz * cc0.z + vw * cc0.w;
      a1 += vx * cc1.x + vy * cc1.y + vz * cc1.z + vw * cc1.w;
    }
    red[t] = a0; red2[t] = a1;                     // reuse reduction arrays
    __syncthreads();
    for (int off = 8; off > 0; off >>= 1) {
      if (seg < off) { red[t] += red[t + off]; red2[t] += red2[t + off]; }
      __syncthreads();
    }
    if (seg == 0) {
      float l0 = red[t] + out_b[0], l1 = red2[t] + out_b[1];
      float mx = fmaxf(l0, l1);
      float e0 = expf(l0 - mx), e1 = expf(l1 - mx);
      float inv = 1.f / (e0 + e1);
      dout[hb * 2 + 0] = e0 * inv;
      dout[hb * 2 + 1] = e1 * inv;
    }
  }
}

extern "C" void kernel_launch(void* const* d_in, const int* in_sizes, int n_in,
                              void* d_out, int out_size, void* d_ws, size_t ws_size,
                              hipStream_t stream) {
  (void)in_sizes; (void)n_in; (void)out_size; (void)ws_size;
  const float* x      = (const float*)d_in[0];
  const float* w      = (const float*)d_in[1];
  const float* gin_W  = (const float*)d_in[2];
  const float* gin_b  = (const float*)d_in[3];
  const float* bn1_g  = (const float*)d_in[4];
  const float* bn1_b  = (const float*)d_in[5];
  const float* lc_W   = (const float*)d_in[6];
  const float* lc_b   = (const float*)d_in[7];
  const float* conv_W = (const float*)d_in[8];
  const float* conv_b = (const float*)d_in[9];
  const float* bn2_g  = (const float*)d_in[10];
  const float* bn2_b  = (const float*)d_in[11];
  const float* out_W  = (const float*)d_in[12];
  const float* out_b  = (const float*)d_in[13];
  float* dout = (float*)d_out;

  char* ws = (char*)d_ws;
  float* spart   = (float*)ws;                                  // 4 MB
  float* h2      = (float*)(ws + (4u << 20));                   // 4 MB
  float* part    = (float*)(ws + (8u << 20));                   // 128 KB (256 x 128 f32)
  float* y2      = (float*)(ws + (8u << 20) + (128u << 10));    // 64 KB
  float* bn2part = (float*)(ws + (8u << 20) + (192u << 10));    // 128 f32
  unsigned* bar  = (unsigned*)(ws + (8u << 20) + (194u << 10)); // ticket counter (never reset)

  k1_spart      <<<dim3(256), dim3(256), 0, stream>>>(x, w, spart);
  k2_gemm_adj_h2<<<dim3(256), dim3(512), 0, stream>>>(x, gin_W, spart, gin_b, dout, h2, part);
  k3_y_head     <<<dim3(64),  dim3(256), 0, stream>>>(h2, part, lc_W, lc_b, bn1_g, bn1_b,
                                                      conv_W, conv_b, bn2_g, bn2_b, out_W, out_b,
                                                      y2, bn2part, dout, bar);
}